// Round 8
// baseline (283.031 us; speedup 1.0000x reference)
//
#include <hip/hip_runtime.h>

#define BB 8
#define CC 192
#define C2 384
#define HH 128
#define WW 128
#define NN 16384
#define NHEADS 4
#define HC 48
#define LTK 196   // LDS row stride in u16 (392 B)
#define LTK2 98   // same in u32
// LDS physical row map: phys(n) = (n>>1) + 64*(n&1)  (de-interleave even/odd cols)

typedef float f32x4 __attribute__((ext_vector_type(4)));
typedef float f32x16 __attribute__((ext_vector_type(16)));
typedef short s16x4 __attribute__((ext_vector_type(4)));
typedef short s16x8 __attribute__((ext_vector_type(8)));
typedef unsigned short u16;
typedef u16 u16x4 __attribute__((ext_vector_type(4)));
typedef u16 u16x8 __attribute__((ext_vector_type(8)));
typedef unsigned int u32;

__device__ __forceinline__ float bfu2f(u32 u16v) {
  return __uint_as_float(u16v << 16);
}
__device__ __forceinline__ u16 f2bfu(float f) {
  u32 u = __float_as_uint(f);
  return (u16)((u + 0x7fffu + ((u >> 16) & 1u)) >> 16);
}
__device__ __forceinline__ s16x8 ldpair(const u16* p) {
  s16x4 lo = *reinterpret_cast<const s16x4*>(p);
  s16x4 hi = *reinterpret_cast<const s16x4*>(p + 16);
  return __builtin_shufflevector(lo, hi, 0, 1, 2, 3, 4, 5, 6, 7);
}
__device__ __forceinline__ s16x8 ldb64pair(const u32* p) {
  s16x4 lo = *reinterpret_cast<const s16x4*>(p);
  s16x4 hi = *reinterpret_cast<const s16x4*>(p + 2);
  return __builtin_shufflevector(lo, hi, 0, 1, 2, 3, 4, 5, 6, 7);
}

// ---------------------------------------------------------------------------
// K0a: w_qkv fp32 -> bf16
// ---------------------------------------------------------------------------
__global__ __launch_bounds__(256) void k0_wcvt(const float* __restrict__ w,
                                               u16* __restrict__ wbf) {
  const int i = (blockIdx.x * 256 + threadIdx.x) * 4;
  f32x4 v = *reinterpret_cast<const f32x4*>(&w[i]);
  u16x4 o;
  o[0] = f2bfu(v[0]); o[1] = f2bfu(v[1]); o[2] = f2bfu(v[2]); o[3] = f2bfu(v[3]);
  *reinterpret_cast<u16x4*>(&wbf[i]) = o;
}

// ---------------------------------------------------------------------------
// K1: qkv[b,o,n] = sum_c wbf[o,c] * x[b,c,n]. Stage x-panel once, 3 o-tiles.
// XCD-chunked n0 swizzle: each XCD gets a contiguous 2048-col panel.
// grid (128, 8), 512 thr.
// ---------------------------------------------------------------------------
__global__ __launch_bounds__(512, 4) void k1_qkv(
    const float* __restrict__ x, const u16* __restrict__ wbf,
    u16* __restrict__ qkv) {
  const int bx = blockIdx.x;
  const int n0 = (((bx & 7) << 4) + (bx >> 3)) << 7;   // XCD-chunked
  const int b  = blockIdx.y;
  __shared__ u16 Xs[128 * LTK];
  u32* Xsw = reinterpret_cast<u32*>(Xs);
  const int t = threadIdx.x, lane = t & 63;
  const int wid = t >> 6, wo = wid >> 1, wn = wid & 1;
  const int l31 = lane & 31, g2 = lane >> 5;

  // ---- stage x[c][n0..n0+127] -> Xs[phys(n)][c-pair] (bf16), once ----
  {
    const int nq = t & 31, cr = t >> 5;        // cr 0..15
    const int kpb = cr >> 1;
    const int jh = cr & 1;
    const int prA = 2 * nq + jh;
    const int prB = 64 + 2 * nq + jh;
    const float* xb = x + (size_t)b * CC * NN + n0 + 4 * nq;
    #pragma unroll 6
    for (int i = 0; i < 12; ++i) {
      f32x4 v = *reinterpret_cast<const f32x4*>(xb + (size_t)(cr + 16 * i) * NN);
      u32 A  = (u32)f2bfu(v[0]) | ((u32)f2bfu(v[1]) << 16);
      u32 Bp = (u32)f2bfu(v[2]) | ((u32)f2bfu(v[3]) << 16);
      u32 oA = __shfl_xor(A, 32);
      u32 oB = __shfl_xor(Bp, 32);
      u32 va, vb;
      if (jh) {
        va = (oB & 0xffffu) | (Bp << 16);
        vb = (oB >> 16) | (Bp & 0xffff0000u);
      } else {
        va = (A & 0xffffu) | (oA << 16);
        vb = (A >> 16) | (oA & 0xffff0000u);
      }
      const int col = kpb + 8 * i;
      Xsw[prA * LTK2 + col] = va;
      Xsw[prB * LTK2 + col] = vb;
    }
  }
  __syncthreads();

  const int nb2 = wn * 32;
  const u32* browE = &Xsw[(nb2 + l31) * LTK2 + 4 * g2];       // even cols
  const u32* browO = &Xsw[(64 + nb2 + l31) * LTK2 + 4 * g2];  // odd cols

  for (int ot = 0; ot < 3; ++ot) {
    const int o0 = ot * 128;
    const u16* wr = wbf + (size_t)(o0 + wo * 32 + l31) * CC + 8 * g2;
    f32x16 accE, accO;
    #pragma unroll
    for (int e = 0; e < 16; ++e) { accE[e] = 0.f; accO[e] = 0.f; }

    s16x8 af0 = *reinterpret_cast<const s16x8*>(wr);
    s16x8 af1 = *reinterpret_cast<const s16x8*>(wr + 16);
    #pragma unroll
    for (int s = 0; s < 6; ++s) {
      s16x8 an0, an1;
      if (s < 5) {
        an0 = *reinterpret_cast<const s16x8*>(wr + (s + 1) * 32);
        an1 = *reinterpret_cast<const s16x8*>(wr + (s + 1) * 32 + 16);
      }
      s16x8 bfE0 = ldb64pair(browE + 16 * s);
      s16x8 bfE1 = ldb64pair(browE + 16 * s + 8);
      s16x8 bfO0 = ldb64pair(browO + 16 * s);
      s16x8 bfO1 = ldb64pair(browO + 16 * s + 8);
      accE = __builtin_amdgcn_mfma_f32_32x32x16_bf16(af0, bfE0, accE, 0, 0, 0);
      accO = __builtin_amdgcn_mfma_f32_32x32x16_bf16(af0, bfO0, accO, 0, 0, 0);
      accE = __builtin_amdgcn_mfma_f32_32x32x16_bf16(af1, bfE1, accE, 0, 0, 0);
      accO = __builtin_amdgcn_mfma_f32_32x32x16_bf16(af1, bfO1, accO, 0, 0, 0);
      af0 = an0; af1 = an1;
    }
    #pragma unroll
    for (int r = 0; r < 16; ++r) {
      const int row = (r & 3) + 8 * (r >> 2) + 4 * g2;
      const u32 pk = (u32)f2bfu(accE[r]) | ((u32)f2bfu(accO[r]) << 16);
      *reinterpret_cast<u32*>(
          &qkv[((size_t)b * C2 + o0 + wo * 32 + row) * NN + n0 + wn * 64 + 2 * l31]) = pk;
    }
  }
}

// ---------------------------------------------------------------------------
// K2: 3x3 depthwise on the V half only (q handled by k23). 8 px/thread.
// grid (B*192*8), 256 thr.
// ---------------------------------------------------------------------------
__global__ __launch_bounds__(256) void k2_dw(
    const u16* __restrict__ qkv, const float* __restrict__ wdw,
    u16* __restrict__ out) {
  const int gid = blockIdx.x;
  const int rb = gid & 7;
  const int p = gid >> 3;            // 0..1535
  const int b = p / 192, cv = p % 192;
  const int ch = CC + cv;            // v channel
  const int plane = b * C2 + ch;
  const int t = threadIdx.x;
  const int row = rb * 16 + (t >> 4);
  const int x0 = (t & 15) * 8;
  const u16* pp = qkv + (size_t)plane * NN;
  const float* wv = wdw + ch * 9;
  float o[8];
  #pragma unroll
  for (int j = 0; j < 8; ++j) o[j] = 0.f;
  #pragma unroll
  for (int dy = 0; dy < 3; ++dy) {
    const int yy = row + dy - 1;
    if ((unsigned)yy < (unsigned)HH) {
      const u16* rp = pp + yy * WW;
      u16x8 m = *reinterpret_cast<const u16x8*>(&rp[x0]);
      float px[10];
      px[0] = (x0 > 0) ? bfu2f(rp[x0 - 1]) : 0.f;
      px[9] = (x0 < 120) ? bfu2f(rp[x0 + 8]) : 0.f;
      #pragma unroll
      for (int j = 0; j < 8; ++j) px[j + 1] = bfu2f(m[j]);
      const float w0 = wv[dy * 3 + 0], w1 = wv[dy * 3 + 1], w2 = wv[dy * 3 + 2];
      #pragma unroll
      for (int j = 0; j < 8; ++j)
        o[j] += w0 * px[j] + w1 * px[j + 1] + w2 * px[j + 2];
    }
  }
  u16x8 ov;
  #pragma unroll
  for (int j = 0; j < 8; ++j) ov[j] = f2bfu(o[j]);
  *reinterpret_cast<u16x8*>(&out[(size_t)plane * NN + row * WW + x0]) = ov;
}

// ---------------------------------------------------------------------------
// K23: fused depthwise-conv (q half) + partial Gram. Block = (row-group, h, b):
// 2 sub-chunks of 4 rows; stage qkv q rows +-1 halo in LDS; conv in registers
// directly into MFMA fragment layout; symmetric Gram MFMA; acc over both
// sub-chunks; 4-wave LDS reduce (aliases staging buffer). q_dw never stored.
// grid (16, 4, 8), 256 thr.
// ---------------------------------------------------------------------------
__global__ __launch_bounds__(256, 2) void k23_convgram(
    const u16* __restrict__ qkv, const float* __restrict__ wdw,
    float* __restrict__ gpart) {
  const int rgRaw = blockIdx.x;
  const int rg = ((rgRaw & 7) << 1) + (rgRaw >> 3);   // XCD-chunked, bijective 16
  const int h = blockIdx.y, b = blockIdx.z;
  const int bh = b * NHEADS + h;
  __shared__ u16 inq[48 * 776];                        // [ch][6*128 + 8 pad]
  const int t = threadIdx.x, lane = t & 63, wv = t >> 6;
  const int l15 = lane & 15, g = lane >> 4;
  const u16* qb = qkv + ((size_t)b * C2 + h * HC) * NN;

  // per-lane conv weights for channels l15, l15+16, l15+32
  float wc[3][9];
  #pragma unroll
  for (int i = 0; i < 3; ++i) {
    const float* wp = wdw + (h * HC + i * 16 + l15) * 9;
    #pragma unroll
    for (int e = 0; e < 9; ++e) wc[i][e] = wp[e];
  }

  f32x4 acc[3][3];
  #pragma unroll
  for (int i = 0; i < 3; ++i)
    #pragma unroll
    for (int j = 0; j < 3; ++j)
      #pragma unroll
      for (int e = 0; e < 4; ++e) acc[i][j][e] = 0.f;

  for (int ck = 0; ck < 2; ++ck) {
    const int R0 = rg * 8 + ck * 4;     // output rows R0..R0+3
    __syncthreads();                    // protect inq before re-stage
    // stage rows R0-1..R0+4 (zero-padded), 48 ch x 768 cols
    #pragma unroll 3
    for (int i = 0; i < 18; ++i) {
      const int idx = t + 256 * i;      // 0..4607
      const int ch = idx / 96, grp = idx % 96;
      const int gn = (R0 - 1) * 128 + grp * 8;
      u16x8 v;
      #pragma unroll
      for (int e = 0; e < 8; ++e) v[e] = 0;
      if (gn >= 0 && gn < NN)
        v = *reinterpret_cast<const u16x8*>(qb + (size_t)ch * NN + gn);
      *reinterpret_cast<u16x8*>(&inq[ch * 776 + grp * 8]) = v;
    }
    __syncthreads();

    // wave wv owns n-slice [wv*128, wv*128+128) of the 512-chunk
    #pragma unroll
    for (int s = 0; s < 4; ++s) {
      s16x8 cf[3];
      #pragma unroll
      for (int i = 0; i < 3; ++i) {
        const u16* cbase = &inq[(i * 16 + l15) * 776];
        u16 o8[8];
        #pragma unroll
        for (int half = 0; half < 2; ++half) {
          const int n = wv * 128 + s * 32 + half * 16 + 4 * g;
          const int row = n >> 7, x0 = n & 127;
          const int br = row + 1;
          #pragma unroll
          for (int j = 0; j < 4; ++j) {
            float sum = 0.f;
            #pragma unroll
            for (int dy = 0; dy < 3; ++dy) {
              const u16* rp = cbase + (br + dy - 1) * 128;
              #pragma unroll
              for (int dx = 0; dx < 3; ++dx) {
                const int xx = x0 + j + dx - 1;
                if (0 <= xx && xx < 128)
                  sum += wc[i][dy * 3 + dx] * bfu2f(rp[xx]);
              }
            }
            o8[half * 4 + j] = f2bfu(sum);
          }
        }
        s16x8 f;
        #pragma unroll
        for (int e = 0; e < 8; ++e) f[e] = (short)o8[e];
        cf[i] = f;
      }
      #pragma unroll
      for (int i = 0; i < 3; ++i)
        #pragma unroll
        for (int j = 0; j < 3; ++j)
          acc[i][j] = __builtin_amdgcn_mfma_f32_16x16x32_bf16(cf[i], cf[j], acc[i][j], 0, 0, 0);
    }
  }

  // 4-wave reduce; red aliases inq (36864 B <= 74496 B)
  __syncthreads();
  float* red = reinterpret_cast<float*>(inq);
  #pragma unroll
  for (int i = 0; i < 3; ++i)
    #pragma unroll
    for (int j = 0; j < 3; ++j)
      #pragma unroll
      for (int r = 0; r < 4; ++r)
        red[wv * 2304 + (i * 16 + 4 * g + r) * 48 + j * 16 + l15] = acc[i][j][r];
  __syncthreads();
  float* gp = gpart + ((size_t)bh * 16 + rg) * 2304;
  for (int idx = t; idx < 2304; idx += 256)
    gp[idx] = red[idx] + red[2304 + idx] + red[4608 + idx] + red[6912 + idx];
}

// ---------------------------------------------------------------------------
// K4: reduce + normalize + softmax (unchanged)
// ---------------------------------------------------------------------------
__global__ __launch_bounds__(256) void k4_soft(
    const float* __restrict__ gpart, const float* __restrict__ temp,
    float* __restrict__ attn) {
  const int bh = blockIdx.x;
  const int h = bh & 3;
  const int t = threadIdx.x;
  __shared__ float G[2304];
  __shared__ float rn[48];
  for (int idx = t; idx < 2304; idx += 256) {
    float s = 0.f;
    #pragma unroll
    for (int c = 0; c < 16; ++c) s += gpart[((size_t)bh * 16 + c) * 2304 + idx];
    G[idx] = s;
  }
  __syncthreads();
  if (t < 48) rn[t] = rsqrtf(G[t * 48 + t]);
  __syncthreads();
  if (t < 48) {
    const float tm = temp[h];
    float v[48];
    float mx = -1e30f;
    #pragma unroll
    for (int j = 0; j < 48; ++j) {
      v[j] = G[t * 48 + j] * rn[t] * rn[j] * tm;
      mx = fmaxf(mx, v[j]);
    }
    float s = 0.f;
    #pragma unroll
    for (int j = 0; j < 48; ++j) { v[j] = expf(v[j] - mx); s += v[j]; }
    const float inv = 1.f / s;
    #pragma unroll
    for (int j = 0; j < 48; ++j)
      attn[(size_t)bh * 2304 + t * 48 + j] = v[j] * inv;
  }
}

// ---------------------------------------------------------------------------
// K5: M = w_proj x blockdiag(attn) -> bf16 (unchanged)
// ---------------------------------------------------------------------------
__global__ __launch_bounds__(192) void k5_M(
    const float* __restrict__ wproj, const float* __restrict__ attn,
    u16* __restrict__ Mbf) {
  const int o = blockIdx.x;
  const int b = blockIdx.y;
  const int d = threadIdx.x;
  const int h = d / HC, dl = d % HC;
  const float* wrow = wproj + o * CC + h * HC;
  const float* at = attn + ((size_t)(b * NHEADS + h)) * 2304;
  float s = 0.f;
  #pragma unroll
  for (int c = 0; c < HC; ++c) s = fmaf(wrow[c], at[c * HC + dl], s);
  Mbf[((size_t)b * CC + o) * CC + d] = f2bfu(s);
}

// ---------------------------------------------------------------------------
// K6: out[b,o,n] = sum_d Mbf[b,o,d] * v[b,d,n]. XCD-chunked n0 swizzle.
// grid (128, 8), 256 thr.
// ---------------------------------------------------------------------------
__global__ __launch_bounds__(256, 4) void k6_out(
    const u16* __restrict__ Mbf, const u16* __restrict__ qkvd,
    float* __restrict__ out) {
  const int bx = blockIdx.x;
  const int n0 = (((bx & 7) << 4) + (bx >> 3)) << 7;   // XCD-chunked
  const int b  = blockIdx.y;
  __shared__ u16 Vs[128 * LTK];
  u32* Vsw = reinterpret_cast<u32*>(Vs);
  const int t = threadIdx.x, lane = t & 63;
  const int wid = t >> 6, wo = wid >> 1, wn = wid & 1;
  const int l31 = lane & 31, g2 = lane >> 5;

  // ---- stage v[d][n0..n0+127] -> Vs[phys(n)][d-pair], once ----
  {
    const int nq = t & 31, cr = t >> 5;        // cr 0..7
    const int kpb = cr >> 1;
    const int jh = cr & 1;
    const int prA = 2 * nq + jh;
    const int prB = 64 + 2 * nq + jh;
    const u16* vbp = qkvd + ((size_t)b * C2 + CC) * NN + n0 + 4 * nq;
    #pragma unroll 6
    for (int i = 0; i < 24; ++i) {
      u16x4 m = *reinterpret_cast<const u16x4*>(vbp + (size_t)(cr + 8 * i) * NN);
      u32 A  = (u32)m[0] | ((u32)m[1] << 16);
      u32 Bp = (u32)m[2] | ((u32)m[3] << 16);
      u32 oA = __shfl_xor(A, 32);
      u32 oB = __shfl_xor(Bp, 32);
      u32 va, vb;
      if (jh) {
        va = (oB & 0xffffu) | (Bp << 16);
        vb = (oB >> 16) | (Bp & 0xffff0000u);
      } else {
        va = (A & 0xffffu) | (oA << 16);
        vb = (A >> 16) | (oA & 0xffff0000u);
      }
      const int col = kpb + 4 * i;
      Vsw[prA * LTK2 + col] = va;
      Vsw[prB * LTK2 + col] = vb;
    }
  }
  __syncthreads();

  const int nb2 = wn * 32;
  const u32* browE = &Vsw[(nb2 + l31) * LTK2 + 4 * g2];
  const u32* browO = &Vsw[(64 + nb2 + l31) * LTK2 + 4 * g2];
  const u16* Ab = Mbf + (size_t)b * CC * CC;

  for (int ot = 0; ot < 3; ++ot) {
    const int o0 = ot * 64;
    const u16* ar = Ab + (size_t)(o0 + wo * 32 + l31) * CC + 8 * g2;
    f32x16 accE, accO;
    #pragma unroll
    for (int e = 0; e < 16; ++e) { accE[e] = 0.f; accO[e] = 0.f; }

    s16x8 af0 = *reinterpret_cast<const s16x8*>(ar);
    s16x8 af1 = *reinterpret_cast<const s16x8*>(ar + 16);
    #pragma unroll
    for (int s = 0; s < 6; ++s) {
      s16x8 an0, an1;
      if (s < 5) {
        an0 = *reinterpret_cast<const s16x8*>(ar + (s + 1) * 32);
        an1 = *reinterpret_cast<const s16x8*>(ar + (s + 1) * 32 + 16);
      }
      s16x8 bfE0 = ldb64pair(browE + 16 * s);
      s16x8 bfE1 = ldb64pair(browE + 16 * s + 8);
      s16x8 bfO0 = ldb64pair(browO + 16 * s);
      s16x8 bfO1 = ldb64pair(browO + 16 * s + 8);
      accE = __builtin_amdgcn_mfma_f32_32x32x16_bf16(af0, bfE0, accE, 0, 0, 0);
      accO = __builtin_amdgcn_mfma_f32_32x32x16_bf16(af0, bfO0, accO, 0, 0, 0);
      accE = __builtin_amdgcn_mfma_f32_32x32x16_bf16(af1, bfE1, accE, 0, 0, 0);
      accO = __builtin_amdgcn_mfma_f32_32x32x16_bf16(af1, bfO1, accO, 0, 0, 0);
      af0 = an0; af1 = an1;
    }
    #pragma unroll
    for (int r = 0; r < 16; ++r) {
      const int row = (r & 3) + 8 * (r >> 2) + 4 * g2;
      float2 st;
      st.x = accE[r];
      st.y = accO[r];
      *reinterpret_cast<float2*>(
          &out[((size_t)b * CC + o0 + wo * 32 + row) * NN + n0 + wn * 64 + 2 * l31]) = st;
    }
  }
}

// ---------------------------------------------------------------------------
extern "C" void kernel_launch(void* const* d_in, const int* in_sizes, int n_in,
                              void* d_out, int out_size, void* d_ws, size_t ws_size,
                              hipStream_t stream) {
  const float* x      = (const float*)d_in[0];
  const float* w_qkv  = (const float*)d_in[1];
  const float* w_dw   = (const float*)d_in[2];
  const float* w_proj = (const float*)d_in[3];
  const float* temp   = (const float*)d_in[4];
  float* out = (float*)d_out;

  const size_t OFF_QKV   = 0;               // bf16  8*384*16384 = 100,663,296
  const size_t OFF_QKVD  = 100663296ULL;    // bf16  same (q half unused now)
  const size_t OFF_GPART = 201326592ULL;    // f32   32*16*2304  = 4,718,592
  const size_t OFF_ATTN  = 206045184ULL;    // f32   32*2304     = 294,912
  const size_t OFF_M     = 206340096ULL;    // bf16  8*192*192   = 589,824
  const size_t OFF_WBF   = 206929920ULL;    // bf16  384*192     = 147,456
  const size_t NEEDED    = 207077376ULL;
  if (ws_size < NEEDED) return;

  char* ws = (char*)d_ws;
  u16* qkv   = (u16*)(ws + OFF_QKV);
  u16* qkvd  = (u16*)(ws + OFF_QKVD);
  float* gpart = (float*)(ws + OFF_GPART);
  float* attn  = (float*)(ws + OFF_ATTN);
  u16* Mbf   = (u16*)(ws + OFF_M);
  u16* wbf   = (u16*)(ws + OFF_WBF);

  k0_wcvt<<<dim3(72), 256, 0, stream>>>(w_qkv, wbf);
  k1_qkv <<<dim3(128, 8), 512, 0, stream>>>(x, wbf, qkv);
  k2_dw  <<<dim3(BB * 192 * 8), 256, 0, stream>>>(qkv, w_dw, qkvd);
  k23_convgram<<<dim3(16, NHEADS, BB), 256, 0, stream>>>(qkv, w_dw, gpart);
  k4_soft<<<dim3(BB * NHEADS), 256, 0, stream>>>(gpart, temp, attn);
  k5_M   <<<dim3(CC, BB), 192, 0, stream>>>(w_proj, attn, Mbf);
  k6_out <<<dim3(128, 8), 256, 0, stream>>>(Mbf, qkvd, out);
}

// Round 9
// 214.843 us; speedup vs baseline: 1.3174x; 1.3174x over previous
//
#include <hip/hip_runtime.h>

#define BB 8
#define CC 192
#define C2 384
#define HH 128
#define WW 128
#define NN 16384
#define NHEADS 4
#define HC 48
#define LTK 196   // LDS row stride in u16 (392 B)
#define LTK2 98   // same in u32
// LDS physical row map: phys(n) = (n>>1) + 64*(n&1)  (de-interleave even/odd cols)

typedef float f32x4 __attribute__((ext_vector_type(4)));
typedef float f32x16 __attribute__((ext_vector_type(16)));
typedef short s16x4 __attribute__((ext_vector_type(4)));
typedef short s16x8 __attribute__((ext_vector_type(8)));
typedef unsigned short u16;
typedef u16 u16x4 __attribute__((ext_vector_type(4)));
typedef u16 u16x8 __attribute__((ext_vector_type(8)));
typedef unsigned int u32;

__device__ __forceinline__ float bfu2f(u32 u16v) {
  return __uint_as_float(u16v << 16);
}
__device__ __forceinline__ u16 f2bfu(float f) {
  u32 u = __float_as_uint(f);
  return (u16)((u + 0x7fffu + ((u >> 16) & 1u)) >> 16);
}
__device__ __forceinline__ s16x8 ldpair(const u16* p) {
  s16x4 lo = *reinterpret_cast<const s16x4*>(p);
  s16x4 hi = *reinterpret_cast<const s16x4*>(p + 16);
  return __builtin_shufflevector(lo, hi, 0, 1, 2, 3, 4, 5, 6, 7);
}
__device__ __forceinline__ s16x8 ldb64pair(const u32* p) {
  s16x4 lo = *reinterpret_cast<const s16x4*>(p);
  s16x4 hi = *reinterpret_cast<const s16x4*>(p + 2);
  return __builtin_shufflevector(lo, hi, 0, 1, 2, 3, 4, 5, 6, 7);
}

// ---------------------------------------------------------------------------
// K0a: w_qkv fp32 -> bf16
// ---------------------------------------------------------------------------
__global__ __launch_bounds__(256) void k0_wcvt(const float* __restrict__ w,
                                               u16* __restrict__ wbf) {
  const int i = (blockIdx.x * 256 + threadIdx.x) * 4;
  f32x4 v = *reinterpret_cast<const f32x4*>(&w[i]);
  u16x4 o;
  o[0] = f2bfu(v[0]); o[1] = f2bfu(v[1]); o[2] = f2bfu(v[2]); o[3] = f2bfu(v[3]);
  *reinterpret_cast<u16x4*>(&wbf[i]) = o;
}

// ---------------------------------------------------------------------------
// K1: qkv[b,o,n] = sum_c wbf[o,c] * x[b,c,n]. Stage x-panel once, 3 o-tiles.
// XCD-chunked n0 swizzle. Per-o-tile: ALL 12 A-fragment loads issued up front
// (MLP covers L2 latency instead of 1-step prefetch). grid (128, 8), 512 thr.
// ---------------------------------------------------------------------------
__global__ __launch_bounds__(512, 4) void k1_qkv(
    const float* __restrict__ x, const u16* __restrict__ wbf,
    u16* __restrict__ qkv) {
  const int bx = blockIdx.x;
  const int n0 = (((bx & 7) << 4) + (bx >> 3)) << 7;   // XCD-chunked, bijective
  const int b  = blockIdx.y;
  __shared__ u16 Xs[128 * LTK];
  u32* Xsw = reinterpret_cast<u32*>(Xs);
  const int t = threadIdx.x, lane = t & 63;
  const int wid = t >> 6, wo = wid >> 1, wn = wid & 1;
  const int l31 = lane & 31, g2 = lane >> 5;

  // ---- stage x[c][n0..n0+127] -> Xs[phys(n)][c-pair] (bf16), once ----
  {
    const int nq = t & 31, cr = t >> 5;        // cr 0..15
    const int kpb = cr >> 1;
    const int jh = cr & 1;
    const int prA = 2 * nq + jh;
    const int prB = 64 + 2 * nq + jh;
    const float* xb = x + (size_t)b * CC * NN + n0 + 4 * nq;
    #pragma unroll 6
    for (int i = 0; i < 12; ++i) {
      f32x4 v = *reinterpret_cast<const f32x4*>(xb + (size_t)(cr + 16 * i) * NN);
      u32 A  = (u32)f2bfu(v[0]) | ((u32)f2bfu(v[1]) << 16);
      u32 Bp = (u32)f2bfu(v[2]) | ((u32)f2bfu(v[3]) << 16);
      u32 oA = __shfl_xor(A, 32);
      u32 oB = __shfl_xor(Bp, 32);
      u32 va, vb;
      if (jh) {
        va = (oB & 0xffffu) | (Bp << 16);
        vb = (oB >> 16) | (Bp & 0xffff0000u);
      } else {
        va = (A & 0xffffu) | (oA << 16);
        vb = (A >> 16) | (oA & 0xffff0000u);
      }
      const int col = kpb + 8 * i;
      Xsw[prA * LTK2 + col] = va;
      Xsw[prB * LTK2 + col] = vb;
    }
  }
  __syncthreads();

  const int nb2 = wn * 32;
  const u32* browE = &Xsw[(nb2 + l31) * LTK2 + 4 * g2];       // even cols
  const u32* browO = &Xsw[(64 + nb2 + l31) * LTK2 + 4 * g2];  // odd cols

  for (int ot = 0; ot < 3; ++ot) {
    const int o0 = ot * 128;
    const u16* wr = wbf + (size_t)(o0 + wo * 32 + l31) * CC + 8 * g2;

    // all 12 A-fragments up front (independent loads -> MLP hides L2 latency)
    s16x8 afA[6], afB[6];
    #pragma unroll
    for (int s = 0; s < 6; ++s) {
      afA[s] = *reinterpret_cast<const s16x8*>(wr + s * 32);
      afB[s] = *reinterpret_cast<const s16x8*>(wr + s * 32 + 16);
    }

    f32x16 accE, accO;
    #pragma unroll
    for (int e = 0; e < 16; ++e) { accE[e] = 0.f; accO[e] = 0.f; }

    #pragma unroll
    for (int s = 0; s < 6; ++s) {
      s16x8 bfE0 = ldb64pair(browE + 16 * s);
      s16x8 bfE1 = ldb64pair(browE + 16 * s + 8);
      s16x8 bfO0 = ldb64pair(browO + 16 * s);
      s16x8 bfO1 = ldb64pair(browO + 16 * s + 8);
      accE = __builtin_amdgcn_mfma_f32_32x32x16_bf16(afA[s], bfE0, accE, 0, 0, 0);
      accO = __builtin_amdgcn_mfma_f32_32x32x16_bf16(afA[s], bfO0, accO, 0, 0, 0);
      accE = __builtin_amdgcn_mfma_f32_32x32x16_bf16(afB[s], bfE1, accE, 0, 0, 0);
      accO = __builtin_amdgcn_mfma_f32_32x32x16_bf16(afB[s], bfO1, accO, 0, 0, 0);
    }
    #pragma unroll
    for (int r = 0; r < 16; ++r) {
      const int row = (r & 3) + 8 * (r >> 2) + 4 * g2;
      const u32 pk = (u32)f2bfu(accE[r]) | ((u32)f2bfu(accO[r]) << 16);
      *reinterpret_cast<u32*>(
          &qkv[((size_t)b * C2 + o0 + wo * 32 + row) * NN + n0 + wn * 64 + 2 * l31]) = pk;
    }
  }
}

// ---------------------------------------------------------------------------
// K2: 3x3 depthwise, all 384 channels, 8 px/thread (r7 version).
// ---------------------------------------------------------------------------
__global__ __launch_bounds__(256) void k2_dw(
    const u16* __restrict__ qkv, const float* __restrict__ wdw,
    u16* __restrict__ out) {
  const int gid = blockIdx.x;
  const int rb = gid & 7;
  const int plane = gid >> 3;
  const int ch = plane % C2;
  const int t = threadIdx.x;
  const int row = rb * 16 + (t >> 4);
  const int x0 = (t & 15) * 8;
  const u16* p = qkv + (size_t)plane * NN;
  const float* wv = wdw + ch * 9;
  float o[8];
  #pragma unroll
  for (int j = 0; j < 8; ++j) o[j] = 0.f;
  #pragma unroll
  for (int dy = 0; dy < 3; ++dy) {
    const int yy = row + dy - 1;
    if ((unsigned)yy < (unsigned)HH) {
      const u16* rp = p + yy * WW;
      u16x8 m = *reinterpret_cast<const u16x8*>(&rp[x0]);
      float px[10];
      px[0] = (x0 > 0) ? bfu2f(rp[x0 - 1]) : 0.f;
      px[9] = (x0 < 120) ? bfu2f(rp[x0 + 8]) : 0.f;
      #pragma unroll
      for (int j = 0; j < 8; ++j) px[j + 1] = bfu2f(m[j]);
      const float w0 = wv[dy * 3 + 0], w1 = wv[dy * 3 + 1], w2 = wv[dy * 3 + 2];
      #pragma unroll
      for (int j = 0; j < 8; ++j)
        o[j] += w0 * px[j] + w1 * px[j + 1] + w2 * px[j + 2];
    }
  }
  u16x8 ov;
  #pragma unroll
  for (int j = 0; j < 8; ++j) ov[j] = f2bfu(o[j]);
  *reinterpret_cast<u16x8*>(&out[(size_t)plane * NN + row * WW + x0]) = ov;
}

// ---------------------------------------------------------------------------
// K3: partial Gram via MFMA (symmetric; same frag both operands). (r7 version)
// ---------------------------------------------------------------------------
__global__ __launch_bounds__(256) void k3_gram(
    const u16* __restrict__ qkvd, float* __restrict__ gpart) {
  const int bh = blockIdx.x, b = bh >> 2, h = bh & 3;
  const int chunk = blockIdx.y;
  const int t = threadIdx.x, lane = t & 63, wv = t >> 6;
  const int l15 = lane & 15, g = lane >> 4;
  __shared__ float red[4][2304];
  const u16* qb = qkvd + ((size_t)b * C2 + h * HC) * NN;

  f32x4 acc[3][3];
  #pragma unroll
  for (int i = 0; i < 3; ++i)
    #pragma unroll
    for (int j = 0; j < 3; ++j)
      #pragma unroll
      for (int e = 0; e < 4; ++e) acc[i][j][e] = 0.f;

  const int nbase = chunk * 1024 + wv * 256;
  #pragma unroll 2
  for (int st = 0; st < 8; ++st) {
    const int n = nbase + st * 32;
    s16x8 cf[3];
    #pragma unroll
    for (int i = 0; i < 3; ++i)
      cf[i] = ldpair(qb + (size_t)(i * 16 + l15) * NN + n + 4 * g);
    #pragma unroll
    for (int i = 0; i < 3; ++i)
      #pragma unroll
      for (int j = 0; j < 3; ++j)
        acc[i][j] = __builtin_amdgcn_mfma_f32_16x16x32_bf16(cf[i], cf[j], acc[i][j], 0, 0, 0);
  }
  #pragma unroll
  for (int i = 0; i < 3; ++i)
    #pragma unroll
    for (int j = 0; j < 3; ++j)
      #pragma unroll
      for (int r = 0; r < 4; ++r)
        red[wv][(i * 16 + 4 * g + r) * 48 + j * 16 + l15] = acc[i][j][r];
  __syncthreads();
  float* gp = gpart + ((size_t)bh * 16 + chunk) * 2304;
  for (int idx = t; idx < 2304; idx += 256)
    gp[idx] = red[0][idx] + red[1][idx] + red[2][idx] + red[3][idx];
}

// ---------------------------------------------------------------------------
// K4: reduce + normalize + softmax (unchanged)
// ---------------------------------------------------------------------------
__global__ __launch_bounds__(256) void k4_soft(
    const float* __restrict__ gpart, const float* __restrict__ temp,
    float* __restrict__ attn) {
  const int bh = blockIdx.x;
  const int h = bh & 3;
  const int t = threadIdx.x;
  __shared__ float G[2304];
  __shared__ float rn[48];
  for (int idx = t; idx < 2304; idx += 256) {
    float s = 0.f;
    #pragma unroll
    for (int c = 0; c < 16; ++c) s += gpart[((size_t)bh * 16 + c) * 2304 + idx];
    G[idx] = s;
  }
  __syncthreads();
  if (t < 48) rn[t] = rsqrtf(G[t * 48 + t]);
  __syncthreads();
  if (t < 48) {
    const float tm = temp[h];
    float v[48];
    float mx = -1e30f;
    #pragma unroll
    for (int j = 0; j < 48; ++j) {
      v[j] = G[t * 48 + j] * rn[t] * rn[j] * tm;
      mx = fmaxf(mx, v[j]);
    }
    float s = 0.f;
    #pragma unroll
    for (int j = 0; j < 48; ++j) { v[j] = expf(v[j] - mx); s += v[j]; }
    const float inv = 1.f / s;
    #pragma unroll
    for (int j = 0; j < 48; ++j)
      attn[(size_t)bh * 2304 + t * 48 + j] = v[j] * inv;
  }
}

// ---------------------------------------------------------------------------
// K5: M = w_proj x blockdiag(attn) -> bf16 (unchanged)
// ---------------------------------------------------------------------------
__global__ __launch_bounds__(192) void k5_M(
    const float* __restrict__ wproj, const float* __restrict__ attn,
    u16* __restrict__ Mbf) {
  const int o = blockIdx.x;
  const int b = blockIdx.y;
  const int d = threadIdx.x;
  const int h = d / HC, dl = d % HC;
  const float* wrow = wproj + o * CC + h * HC;
  const float* at = attn + ((size_t)(b * NHEADS + h)) * 2304;
  float s = 0.f;
  #pragma unroll
  for (int c = 0; c < HC; ++c) s = fmaf(wrow[c], at[c * HC + dl], s);
  Mbf[((size_t)b * CC + o) * CC + d] = f2bfu(s);
}

// ---------------------------------------------------------------------------
// K6: out[b,o,n] = sum_d Mbf[b,o,d] * v[b,d,n]. Stage v-panel once; 3 o-tiles
// of 64; XCD-chunked swizzle; all 12 A-frag loads up front. grid (128,8), 256t.
// ---------------------------------------------------------------------------
__global__ __launch_bounds__(256, 4) void k6_out(
    const u16* __restrict__ Mbf, const u16* __restrict__ qkvd,
    float* __restrict__ out) {
  const int bx = blockIdx.x;
  const int n0 = (((bx & 7) << 4) + (bx >> 3)) << 7;   // XCD-chunked, bijective
  const int b  = blockIdx.y;
  __shared__ u16 Vs[128 * LTK];
  u32* Vsw = reinterpret_cast<u32*>(Vs);
  const int t = threadIdx.x, lane = t & 63;
  const int wid = t >> 6, wo = wid >> 1, wn = wid & 1;
  const int l31 = lane & 31, g2 = lane >> 5;

  // ---- stage v[d][n0..n0+127] -> Vs[phys(n)][d-pair], once ----
  {
    const int nq = t & 31, cr = t >> 5;        // cr 0..7
    const int kpb = cr >> 1;
    const int jh = cr & 1;
    const int prA = 2 * nq + jh;
    const int prB = 64 + 2 * nq + jh;
    const u16* vbp = qkvd + ((size_t)b * C2 + CC) * NN + n0 + 4 * nq;
    #pragma unroll 6
    for (int i = 0; i < 24; ++i) {
      u16x4 m = *reinterpret_cast<const u16x4*>(vbp + (size_t)(cr + 8 * i) * NN);
      u32 A  = (u32)m[0] | ((u32)m[1] << 16);
      u32 Bp = (u32)m[2] | ((u32)m[3] << 16);
      u32 oA = __shfl_xor(A, 32);
      u32 oB = __shfl_xor(Bp, 32);
      u32 va, vb;
      if (jh) {
        va = (oB & 0xffffu) | (Bp << 16);
        vb = (oB >> 16) | (Bp & 0xffff0000u);
      } else {
        va = (A & 0xffffu) | (oA << 16);
        vb = (A >> 16) | (oA & 0xffff0000u);
      }
      const int col = kpb + 4 * i;
      Vsw[prA * LTK2 + col] = va;
      Vsw[prB * LTK2 + col] = vb;
    }
  }
  __syncthreads();

  const int nb2 = wn * 32;
  const u32* browE = &Vsw[(nb2 + l31) * LTK2 + 4 * g2];
  const u32* browO = &Vsw[(64 + nb2 + l31) * LTK2 + 4 * g2];
  const u16* Ab = Mbf + (size_t)b * CC * CC;

  for (int ot = 0; ot < 3; ++ot) {
    const int o0 = ot * 64;
    const u16* ar = Ab + (size_t)(o0 + wo * 32 + l31) * CC + 8 * g2;

    s16x8 afA[6], afB[6];
    #pragma unroll
    for (int s = 0; s < 6; ++s) {
      afA[s] = *reinterpret_cast<const s16x8*>(ar + s * 32);
      afB[s] = *reinterpret_cast<const s16x8*>(ar + s * 32 + 16);
    }

    f32x16 accE, accO;
    #pragma unroll
    for (int e = 0; e < 16; ++e) { accE[e] = 0.f; accO[e] = 0.f; }

    #pragma unroll
    for (int s = 0; s < 6; ++s) {
      s16x8 bfE0 = ldb64pair(browE + 16 * s);
      s16x8 bfE1 = ldb64pair(browE + 16 * s + 8);
      s16x8 bfO0 = ldb64pair(browO + 16 * s);
      s16x8 bfO1 = ldb64pair(browO + 16 * s + 8);
      accE = __builtin_amdgcn_mfma_f32_32x32x16_bf16(afA[s], bfE0, accE, 0, 0, 0);
      accO = __builtin_amdgcn_mfma_f32_32x32x16_bf16(afA[s], bfO0, accO, 0, 0, 0);
      accE = __builtin_amdgcn_mfma_f32_32x32x16_bf16(afB[s], bfE1, accE, 0, 0, 0);
      accO = __builtin_amdgcn_mfma_f32_32x32x16_bf16(afB[s], bfO1, accO, 0, 0, 0);
    }
    #pragma unroll
    for (int r = 0; r < 16; ++r) {
      const int row = (r & 3) + 8 * (r >> 2) + 4 * g2;
      float2 st;
      st.x = accE[r];
      st.y = accO[r];
      *reinterpret_cast<float2*>(
          &out[((size_t)b * CC + o0 + wo * 32 + row) * NN + n0 + wn * 64 + 2 * l31]) = st;
    }
  }
}

// ---------------------------------------------------------------------------
extern "C" void kernel_launch(void* const* d_in, const int* in_sizes, int n_in,
                              void* d_out, int out_size, void* d_ws, size_t ws_size,
                              hipStream_t stream) {
  const float* x      = (const float*)d_in[0];
  const float* w_qkv  = (const float*)d_in[1];
  const float* w_dw   = (const float*)d_in[2];
  const float* w_proj = (const float*)d_in[3];
  const float* temp   = (const float*)d_in[4];
  float* out = (float*)d_out;

  const size_t OFF_QKV   = 0;               // bf16  8*384*16384 = 100,663,296
  const size_t OFF_QKVD  = 100663296ULL;    // bf16  same
  const size_t OFF_GPART = 201326592ULL;    // f32   32*16*2304  = 4,718,592
  const size_t OFF_ATTN  = 206045184ULL;    // f32   32*2304     = 294,912
  const size_t OFF_M     = 206340096ULL;    // bf16  8*192*192   = 589,824
  const size_t OFF_WBF   = 206929920ULL;    // bf16  384*192     = 147,456
  const size_t NEEDED    = 207077376ULL;
  if (ws_size < NEEDED) return;

  char* ws = (char*)d_ws;
  u16* qkv   = (u16*)(ws + OFF_QKV);
  u16* qkvd  = (u16*)(ws + OFF_QKVD);
  float* gpart = (float*)(ws + OFF_GPART);
  float* attn  = (float*)(ws + OFF_ATTN);
  u16* Mbf   = (u16*)(ws + OFF_M);
  u16* wbf   = (u16*)(ws + OFF_WBF);

  k0_wcvt<<<dim3(72), 256, 0, stream>>>(w_qkv, wbf);
  k1_qkv <<<dim3(128, 8), 512, 0, stream>>>(x, wbf, qkv);
  k2_dw  <<<dim3(BB * C2 * 8), 256, 0, stream>>>(qkv, w_dw, qkvd);
  k3_gram<<<dim3(BB * NHEADS, 16), 256, 0, stream>>>(qkvd, gpart);
  k4_soft<<<dim3(BB * NHEADS), 256, 0, stream>>>(gpart, temp, attn);
  k5_M   <<<dim3(CC, BB), 192, 0, stream>>>(w_proj, attn, Mbf);
  k6_out <<<dim3(128, 8), 256, 0, stream>>>(Mbf, qkvd, out);
}

// Round 10
// 213.766 us; speedup vs baseline: 1.3240x; 1.0050x over previous
//
#include <hip/hip_runtime.h>

#define BB 8
#define CC 192
#define C2 384
#define HH 128
#define WW 128
#define NN 16384
#define NHEADS 4
#define HC 48
#define LTK 196   // LDS row stride in u16 (392 B)
#define LTK2 98   // same in u32
// k1 LDS physical row map (256-col panel): phys(n) = (n>>1) + 128*(n&1)
// k6 LDS physical row map (128-col panel): phys(n) = (n>>1) +  64*(n&1)

typedef float f32x4 __attribute__((ext_vector_type(4)));
typedef float f32x16 __attribute__((ext_vector_type(16)));
typedef short s16x4 __attribute__((ext_vector_type(4)));
typedef short s16x8 __attribute__((ext_vector_type(8)));
typedef unsigned short u16;
typedef u16 u16x4 __attribute__((ext_vector_type(4)));
typedef u16 u16x8 __attribute__((ext_vector_type(8)));
typedef unsigned int u32;

__device__ __forceinline__ float bfu2f(u32 u16v) {
  return __uint_as_float(u16v << 16);
}
__device__ __forceinline__ u16 f2bfu(float f) {
  u32 u = __float_as_uint(f);
  return (u16)((u + 0x7fffu + ((u >> 16) & 1u)) >> 16);
}
__device__ __forceinline__ s16x8 ldpair(const u16* p) {
  s16x4 lo = *reinterpret_cast<const s16x4*>(p);
  s16x4 hi = *reinterpret_cast<const s16x4*>(p + 16);
  return __builtin_shufflevector(lo, hi, 0, 1, 2, 3, 4, 5, 6, 7);
}
__device__ __forceinline__ s16x8 ldb64pair(const u32* p) {
  s16x4 lo = *reinterpret_cast<const s16x4*>(p);
  s16x4 hi = *reinterpret_cast<const s16x4*>(p + 2);
  return __builtin_shufflevector(lo, hi, 0, 1, 2, 3, 4, 5, 6, 7);
}

// ---------------------------------------------------------------------------
// K0a: w_qkv fp32 -> bf16
// ---------------------------------------------------------------------------
__global__ __launch_bounds__(256) void k0_wcvt(const float* __restrict__ w,
                                               u16* __restrict__ wbf) {
  const int i = (blockIdx.x * 256 + threadIdx.x) * 4;
  f32x4 v = *reinterpret_cast<const f32x4*>(&w[i]);
  u16x4 o;
  o[0] = f2bfu(v[0]); o[1] = f2bfu(v[1]); o[2] = f2bfu(v[2]); o[3] = f2bfu(v[3]);
  *reinterpret_cast<u16x4*>(&wbf[i]) = o;
}

// ---------------------------------------------------------------------------
// K1: qkv[b,o,n] = sum_c wbf[o,c] * x[b,c,n]. 256-col n-panel staged once
// (fused f32->bf16, [phys(n)][c-pair], 98 KB LDS); 3 o-tiles of 128.
// 16 waves = 4o x 4n; wave-tile 32o x 64n (E/O col frags, packed u32 stores).
// Staging: pair-loads (c, c+1) per lane -> 1 KB/instr read granule.
// grid (64, 8), 1024 thr.
// ---------------------------------------------------------------------------
__global__ __launch_bounds__(1024, 4) void k1_qkv(
    const float* __restrict__ x, const u16* __restrict__ wbf,
    u16* __restrict__ qkv) {
  const int bx = blockIdx.x;
  const int n0 = (((bx & 7) << 3) + (bx >> 3)) << 8;   // XCD-chunked, bijective 64
  const int b  = blockIdx.y;
  __shared__ u16 Xs[256 * LTK];                        // 100352 B
  u32* Xsw = reinterpret_cast<u32*>(Xs);
  const int t = threadIdx.x, lane = t & 63;
  const int wid = t >> 6, wo = wid >> 2, wn = wid & 3;
  const int l31 = lane & 31, g2 = lane >> 5;

  // ---- stage x[c][n0..n0+255] -> Xs[phys(n)][c-pair], once ----
  {
    const int q = t & 63;                 // 4-col group (cols 4q..4q+3)
    const int pb = t >> 6;                // c-pair base (0..15)
    const float* xb = x + (size_t)b * CC * NN + n0 + 4 * q;
    #pragma unroll
    for (int i = 0; i < 6; ++i) {
      const int p = pb + 16 * i;          // c-pair 0..95
      f32x4 r0 = *reinterpret_cast<const f32x4*>(xb + (size_t)(2 * p) * NN);
      f32x4 r1 = *reinterpret_cast<const f32x4*>(xb + (size_t)(2 * p + 1) * NN);
      u32 w0 = (u32)f2bfu(r0[0]) | ((u32)f2bfu(r1[0]) << 16);
      u32 w1 = (u32)f2bfu(r0[1]) | ((u32)f2bfu(r1[1]) << 16);
      u32 w2 = (u32)f2bfu(r0[2]) | ((u32)f2bfu(r1[2]) << 16);
      u32 w3 = (u32)f2bfu(r0[3]) | ((u32)f2bfu(r1[3]) << 16);
      // n = 4q+j -> phys: j0:2q, j1:2q+128, j2:2q+1, j3:2q+129
      Xsw[(2 * q) * LTK2 + p]       = w0;
      Xsw[(2 * q + 128) * LTK2 + p] = w1;
      Xsw[(2 * q + 1) * LTK2 + p]   = w2;
      Xsw[(2 * q + 129) * LTK2 + p] = w3;
    }
  }
  __syncthreads();

  const u32* browE = &Xsw[(wn * 32 + l31) * LTK2 + 4 * g2];        // even n
  const u32* browO = &Xsw[(128 + wn * 32 + l31) * LTK2 + 4 * g2];  // odd n

  for (int ot = 0; ot < 3; ++ot) {
    const int o0 = ot * 128;
    const u16* wr = wbf + (size_t)(o0 + wo * 32 + l31) * CC + 8 * g2;

    s16x8 afA[6], afB[6];
    #pragma unroll
    for (int s = 0; s < 6; ++s) {
      afA[s] = *reinterpret_cast<const s16x8*>(wr + s * 32);
      afB[s] = *reinterpret_cast<const s16x8*>(wr + s * 32 + 16);
    }

    f32x16 accE, accO;
    #pragma unroll
    for (int e = 0; e < 16; ++e) { accE[e] = 0.f; accO[e] = 0.f; }

    #pragma unroll
    for (int s = 0; s < 6; ++s) {
      s16x8 bfE0 = ldb64pair(browE + 16 * s);
      s16x8 bfE1 = ldb64pair(browE + 16 * s + 8);
      s16x8 bfO0 = ldb64pair(browO + 16 * s);
      s16x8 bfO1 = ldb64pair(browO + 16 * s + 8);
      accE = __builtin_amdgcn_mfma_f32_32x32x16_bf16(afA[s], bfE0, accE, 0, 0, 0);
      accO = __builtin_amdgcn_mfma_f32_32x32x16_bf16(afA[s], bfO0, accO, 0, 0, 0);
      accE = __builtin_amdgcn_mfma_f32_32x32x16_bf16(afB[s], bfE1, accE, 0, 0, 0);
      accO = __builtin_amdgcn_mfma_f32_32x32x16_bf16(afB[s], bfO1, accO, 0, 0, 0);
    }
    #pragma unroll
    for (int r = 0; r < 16; ++r) {
      const int row = (r & 3) + 8 * (r >> 2) + 4 * g2;
      const u32 pk = (u32)f2bfu(accE[r]) | ((u32)f2bfu(accO[r]) << 16);
      *reinterpret_cast<u32*>(
          &qkv[((size_t)b * C2 + o0 + wo * 32 + row) * NN + n0 + wn * 64 + 2 * l31]) = pk;
    }
  }
}

// ---------------------------------------------------------------------------
// K2: 3x3 depthwise, all 384 channels, 8 px/thread (unchanged).
// ---------------------------------------------------------------------------
__global__ __launch_bounds__(256) void k2_dw(
    const u16* __restrict__ qkv, const float* __restrict__ wdw,
    u16* __restrict__ out) {
  const int gid = blockIdx.x;
  const int rb = gid & 7;
  const int plane = gid >> 3;
  const int ch = plane % C2;
  const int t = threadIdx.x;
  const int row = rb * 16 + (t >> 4);
  const int x0 = (t & 15) * 8;
  const u16* p = qkv + (size_t)plane * NN;
  const float* wv = wdw + ch * 9;
  float o[8];
  #pragma unroll
  for (int j = 0; j < 8; ++j) o[j] = 0.f;
  #pragma unroll
  for (int dy = 0; dy < 3; ++dy) {
    const int yy = row + dy - 1;
    if ((unsigned)yy < (unsigned)HH) {
      const u16* rp = p + yy * WW;
      u16x8 m = *reinterpret_cast<const u16x8*>(&rp[x0]);
      float px[10];
      px[0] = (x0 > 0) ? bfu2f(rp[x0 - 1]) : 0.f;
      px[9] = (x0 < 120) ? bfu2f(rp[x0 + 8]) : 0.f;
      #pragma unroll
      for (int j = 0; j < 8; ++j) px[j + 1] = bfu2f(m[j]);
      const float w0 = wv[dy * 3 + 0], w1 = wv[dy * 3 + 1], w2 = wv[dy * 3 + 2];
      #pragma unroll
      for (int j = 0; j < 8; ++j)
        o[j] += w0 * px[j] + w1 * px[j + 1] + w2 * px[j + 2];
    }
  }
  u16x8 ov;
  #pragma unroll
  for (int j = 0; j < 8; ++j) ov[j] = f2bfu(o[j]);
  *reinterpret_cast<u16x8*>(&out[(size_t)plane * NN + row * WW + x0]) = ov;
}

// ---------------------------------------------------------------------------
// K3: partial Gram via MFMA (unchanged).
// ---------------------------------------------------------------------------
__global__ __launch_bounds__(256) void k3_gram(
    const u16* __restrict__ qkvd, float* __restrict__ gpart) {
  const int bh = blockIdx.x, b = bh >> 2, h = bh & 3;
  const int chunk = blockIdx.y;
  const int t = threadIdx.x, lane = t & 63, wv = t >> 6;
  const int l15 = lane & 15, g = lane >> 4;
  __shared__ float red[4][2304];
  const u16* qb = qkvd + ((size_t)b * C2 + h * HC) * NN;

  f32x4 acc[3][3];
  #pragma unroll
  for (int i = 0; i < 3; ++i)
    #pragma unroll
    for (int j = 0; j < 3; ++j)
      #pragma unroll
      for (int e = 0; e < 4; ++e) acc[i][j][e] = 0.f;

  const int nbase = chunk * 1024 + wv * 256;
  #pragma unroll 2
  for (int st = 0; st < 8; ++st) {
    const int n = nbase + st * 32;
    s16x8 cf[3];
    #pragma unroll
    for (int i = 0; i < 3; ++i)
      cf[i] = ldpair(qb + (size_t)(i * 16 + l15) * NN + n + 4 * g);
    #pragma unroll
    for (int i = 0; i < 3; ++i)
      #pragma unroll
      for (int j = 0; j < 3; ++j)
        acc[i][j] = __builtin_amdgcn_mfma_f32_16x16x32_bf16(cf[i], cf[j], acc[i][j], 0, 0, 0);
  }
  #pragma unroll
  for (int i = 0; i < 3; ++i)
    #pragma unroll
    for (int j = 0; j < 3; ++j)
      #pragma unroll
      for (int r = 0; r < 4; ++r)
        red[wv][(i * 16 + 4 * g + r) * 48 + j * 16 + l15] = acc[i][j][r];
  __syncthreads();
  float* gp = gpart + ((size_t)bh * 16 + chunk) * 2304;
  for (int idx = t; idx < 2304; idx += 256)
    gp[idx] = red[0][idx] + red[1][idx] + red[2][idx] + red[3][idx];
}

// ---------------------------------------------------------------------------
// K4: reduce + normalize + softmax (unchanged)
// ---------------------------------------------------------------------------
__global__ __launch_bounds__(256) void k4_soft(
    const float* __restrict__ gpart, const float* __restrict__ temp,
    float* __restrict__ attn) {
  const int bh = blockIdx.x;
  const int h = bh & 3;
  const int t = threadIdx.x;
  __shared__ float G[2304];
  __shared__ float rn[48];
  for (int idx = t; idx < 2304; idx += 256) {
    float s = 0.f;
    #pragma unroll
    for (int c = 0; c < 16; ++c) s += gpart[((size_t)bh * 16 + c) * 2304 + idx];
    G[idx] = s;
  }
  __syncthreads();
  if (t < 48) rn[t] = rsqrtf(G[t * 48 + t]);
  __syncthreads();
  if (t < 48) {
    const float tm = temp[h];
    float v[48];
    float mx = -1e30f;
    #pragma unroll
    for (int j = 0; j < 48; ++j) {
      v[j] = G[t * 48 + j] * rn[t] * rn[j] * tm;
      mx = fmaxf(mx, v[j]);
    }
    float s = 0.f;
    #pragma unroll
    for (int j = 0; j < 48; ++j) { v[j] = expf(v[j] - mx); s += v[j]; }
    const float inv = 1.f / s;
    #pragma unroll
    for (int j = 0; j < 48; ++j)
      attn[(size_t)bh * 2304 + t * 48 + j] = v[j] * inv;
  }
}

// ---------------------------------------------------------------------------
// K5: M = w_proj x blockdiag(attn) -> bf16 (unchanged)
// ---------------------------------------------------------------------------
__global__ __launch_bounds__(192) void k5_M(
    const float* __restrict__ wproj, const float* __restrict__ attn,
    u16* __restrict__ Mbf) {
  const int o = blockIdx.x;
  const int b = blockIdx.y;
  const int d = threadIdx.x;
  const int h = d / HC, dl = d % HC;
  const float* wrow = wproj + o * CC + h * HC;
  const float* at = attn + ((size_t)(b * NHEADS + h)) * 2304;
  float s = 0.f;
  #pragma unroll
  for (int c = 0; c < HC; ++c) s = fmaf(wrow[c], at[c * HC + dl], s);
  Mbf[((size_t)b * CC + o) * CC + d] = f2bfu(s);
}

// ---------------------------------------------------------------------------
// K6: out[b,o,n] = sum_d Mbf[b,o,d] * v[b,d,n] (unchanged r9 version).
// ---------------------------------------------------------------------------
__global__ __launch_bounds__(256, 4) void k6_out(
    const u16* __restrict__ Mbf, const u16* __restrict__ qkvd,
    float* __restrict__ out) {
  const int bx = blockIdx.x;
  const int n0 = (((bx & 7) << 4) + (bx >> 3)) << 7;   // XCD-chunked, bijective
  const int b  = blockIdx.y;
  __shared__ u16 Vs[128 * LTK];
  u32* Vsw = reinterpret_cast<u32*>(Vs);
  const int t = threadIdx.x, lane = t & 63;
  const int wid = t >> 6, wo = wid >> 1, wn = wid & 1;
  const int l31 = lane & 31, g2 = lane >> 5;

  {
    const int nq = t & 31, cr = t >> 5;        // cr 0..7
    const int kpb = cr >> 1;
    const int jh = cr & 1;
    const int prA = 2 * nq + jh;
    const int prB = 64 + 2 * nq + jh;
    const u16* vbp = qkvd + ((size_t)b * C2 + CC) * NN + n0 + 4 * nq;
    #pragma unroll 6
    for (int i = 0; i < 24; ++i) {
      u16x4 m = *reinterpret_cast<const u16x4*>(vbp + (size_t)(cr + 8 * i) * NN);
      u32 A  = (u32)m[0] | ((u32)m[1] << 16);
      u32 Bp = (u32)m[2] | ((u32)m[3] << 16);
      u32 oA = __shfl_xor(A, 32);
      u32 oB = __shfl_xor(Bp, 32);
      u32 va, vb;
      if (jh) {
        va = (oB & 0xffffu) | (Bp << 16);
        vb = (oB >> 16) | (Bp & 0xffff0000u);
      } else {
        va = (A & 0xffffu) | (oA << 16);
        vb = (A >> 16) | (oA & 0xffff0000u);
      }
      const int col = kpb + 4 * i;
      Vsw[prA * LTK2 + col] = va;
      Vsw[prB * LTK2 + col] = vb;
    }
  }
  __syncthreads();

  const int nb2 = wn * 32;
  const u32* browE = &Vsw[(nb2 + l31) * LTK2 + 4 * g2];
  const u32* browO = &Vsw[(64 + nb2 + l31) * LTK2 + 4 * g2];
  const u16* Ab = Mbf + (size_t)b * CC * CC;

  for (int ot = 0; ot < 3; ++ot) {
    const int o0 = ot * 64;
    const u16* ar = Ab + (size_t)(o0 + wo * 32 + l31) * CC + 8 * g2;

    s16x8 afA[6], afB[6];
    #pragma unroll
    for (int s = 0; s < 6; ++s) {
      afA[s] = *reinterpret_cast<const s16x8*>(ar + s * 32);
      afB[s] = *reinterpret_cast<const s16x8*>(ar + s * 32 + 16);
    }

    f32x16 accE, accO;
    #pragma unroll
    for (int e = 0; e < 16; ++e) { accE[e] = 0.f; accO[e] = 0.f; }

    #pragma unroll
    for (int s = 0; s < 6; ++s) {
      s16x8 bfE0 = ldb64pair(browE + 16 * s);
      s16x8 bfE1 = ldb64pair(browE + 16 * s + 8);
      s16x8 bfO0 = ldb64pair(browO + 16 * s);
      s16x8 bfO1 = ldb64pair(browO + 16 * s + 8);
      accE = __builtin_amdgcn_mfma_f32_32x32x16_bf16(afA[s], bfE0, accE, 0, 0, 0);
      accO = __builtin_amdgcn_mfma_f32_32x32x16_bf16(afA[s], bfO0, accO, 0, 0, 0);
      accE = __builtin_amdgcn_mfma_f32_32x32x16_bf16(afB[s], bfE1, accE, 0, 0, 0);
      accO = __builtin_amdgcn_mfma_f32_32x32x16_bf16(afB[s], bfO1, accO, 0, 0, 0);
    }
    #pragma unroll
    for (int r = 0; r < 16; ++r) {
      const int row = (r & 3) + 8 * (r >> 2) + 4 * g2;
      float2 st;
      st.x = accE[r];
      st.y = accO[r];
      *reinterpret_cast<float2*>(
          &out[((size_t)b * CC + o0 + wo * 32 + row) * NN + n0 + wn * 64 + 2 * l31]) = st;
    }
  }
}

// ---------------------------------------------------------------------------
extern "C" void kernel_launch(void* const* d_in, const int* in_sizes, int n_in,
                              void* d_out, int out_size, void* d_ws, size_t ws_size,
                              hipStream_t stream) {
  const float* x      = (const float*)d_in[0];
  const float* w_qkv  = (const float*)d_in[1];
  const float* w_dw   = (const float*)d_in[2];
  const float* w_proj = (const float*)d_in[3];
  const float* temp   = (const float*)d_in[4];
  float* out = (float*)d_out;

  const size_t OFF_QKV   = 0;               // bf16  8*384*16384 = 100,663,296
  const size_t OFF_QKVD  = 100663296ULL;    // bf16  same
  const size_t OFF_GPART = 201326592ULL;    // f32   32*16*2304  = 4,718,592
  const size_t OFF_ATTN  = 206045184ULL;    // f32   32*2304     = 294,912
  const size_t OFF_M     = 206340096ULL;    // bf16  8*192*192   = 589,824
  const size_t OFF_WBF   = 206929920ULL;    // bf16  384*192     = 147,456
  const size_t NEEDED    = 207077376ULL;
  if (ws_size < NEEDED) return;

  char* ws = (char*)d_ws;
  u16* qkv   = (u16*)(ws + OFF_QKV);
  u16* qkvd  = (u16*)(ws + OFF_QKVD);
  float* gpart = (float*)(ws + OFF_GPART);
  float* attn  = (float*)(ws + OFF_ATTN);
  u16* Mbf   = (u16*)(ws + OFF_M);
  u16* wbf   = (u16*)(ws + OFF_WBF);

  k0_wcvt<<<dim3(72), 256, 0, stream>>>(w_qkv, wbf);
  k1_qkv <<<dim3(64, 8), 1024, 0, stream>>>(x, wbf, qkv);
  k2_dw  <<<dim3(BB * C2 * 8), 256, 0, stream>>>(qkv, w_dw, qkvd);
  k3_gram<<<dim3(BB * NHEADS, 16), 256, 0, stream>>>(qkvd, gpart);
  k4_soft<<<dim3(BB * NHEADS), 256, 0, stream>>>(gpart, temp, attn);
  k5_M   <<<dim3(CC, BB), 192, 0, stream>>>(w_proj, attn, Mbf);
  k6_out <<<dim3(128, 8), 256, 0, stream>>>(Mbf, qkvd, out);
}